// Round 14
// baseline (524.863 us; speedup 1.0000x reference)
//
#include <hip/hip_runtime.h>
#include <cstdint>
#include <cstddef>

// ---- problem constants ----
#define MM 8192
#define NN 4096
#define KK 4096
#define PI_UNITF 0.006135923151542565f   // (pi/2)/256
#define INV_PI_UNITF (1.0f / PI_UNITF)

// ---- GEMM tiling ----
#define BM 128
#define BN 256
#define BK 64
#define NKT (KK / BK)   // 64 K-tiles
#define NBUF 4          // LDS buffers (prefetch depth 3)

// per-buffer LDS layout: A_lo [128][64] | A_hi [128][64] | B [256][64]
#define OFF_AHI  (BM * BK)          // 8192
#define OFF_B    (2 * BM * BK)      // 16384
#define BUF_BYTES (2 * BM * BK + BN * BK)   // 32768

typedef int int4v  __attribute__((ext_vector_type(4)));
typedef int int16v __attribute__((ext_vector_type(16)));

typedef const __attribute__((address_space(1))) void* as1_cptr;
typedef __attribute__((address_space(3))) void* as3_ptr;

__device__ __forceinline__ uint32_t pack4(int b0, int b1, int b2, int b3) {
    return ((uint32_t)(uint8_t)b0) | ((uint32_t)(uint8_t)b1 << 8) |
           ((uint32_t)(uint8_t)b2 << 16) | ((uint32_t)(uint8_t)b3 << 24);
}

// Quantize x: ix = rint(x/D); split ix = hi*256 + lo.
__global__ __launch_bounds__(256) void quant_x_kernel(
    const float* __restrict__ x, uint32_t* __restrict__ lo,
    uint32_t* __restrict__ hi, int n4)
{
    const int stride = gridDim.x * blockDim.x;
    for (int i = blockIdx.x * blockDim.x + threadIdx.x; i < n4; i += stride) {
        float4 v = reinterpret_cast<const float4*>(x)[i];
        int q0 = (int)rintf(v.x * INV_PI_UNITF);
        int q1 = (int)rintf(v.y * INV_PI_UNITF);
        int q2 = (int)rintf(v.z * INV_PI_UNITF);
        int q3 = (int)rintf(v.w * INV_PI_UNITF);
        int l0 = (int8_t)(q0 & 0xff), l1 = (int8_t)(q1 & 0xff);
        int l2 = (int8_t)(q2 & 0xff), l3 = (int8_t)(q3 & 0xff);
        lo[i] = pack4(l0, l1, l2, l3);
        hi[i] = pack4((q0 - l0) >> 8, (q1 - l1) >> 8,
                      (q2 - l2) >> 8, (q3 - l3) >> 8);
    }
}

// Quantize w: iw = rint(w/D), fits int8.
__global__ __launch_bounds__(256) void quant_w_kernel(
    const float* __restrict__ w, uint32_t* __restrict__ w8, int n4)
{
    const int stride = gridDim.x * blockDim.x;
    for (int i = blockIdx.x * blockDim.x + threadIdx.x; i < n4; i += stride) {
        float4 v = reinterpret_cast<const float4*>(w)[i];
        w8[i] = pack4((int)rintf(v.x * INV_PI_UNITF),
                      (int)rintf(v.y * INV_PI_UNITF),
                      (int)rintf(v.z * INV_PI_UNITF),
                      (int)rintf(v.w * INV_PI_UNITF));
    }
}

#define MFMA16(aL0, aL1, aH0, aH1, b0, b1, b2, b3)                                \
    accL[0][0] = __builtin_amdgcn_mfma_i32_32x32x32_i8(aL0, b0, accL[0][0],0,0,0);\
    accL[0][1] = __builtin_amdgcn_mfma_i32_32x32x32_i8(aL0, b1, accL[0][1],0,0,0);\
    accL[0][2] = __builtin_amdgcn_mfma_i32_32x32x32_i8(aL0, b2, accL[0][2],0,0,0);\
    accL[0][3] = __builtin_amdgcn_mfma_i32_32x32x32_i8(aL0, b3, accL[0][3],0,0,0);\
    accL[1][0] = __builtin_amdgcn_mfma_i32_32x32x32_i8(aL1, b0, accL[1][0],0,0,0);\
    accL[1][1] = __builtin_amdgcn_mfma_i32_32x32x32_i8(aL1, b1, accL[1][1],0,0,0);\
    accL[1][2] = __builtin_amdgcn_mfma_i32_32x32x32_i8(aL1, b2, accL[1][2],0,0,0);\
    accL[1][3] = __builtin_amdgcn_mfma_i32_32x32x32_i8(aL1, b3, accL[1][3],0,0,0);\
    accH[0][0] = __builtin_amdgcn_mfma_i32_32x32x32_i8(aH0, b0, accH[0][0],0,0,0);\
    accH[0][1] = __builtin_amdgcn_mfma_i32_32x32x32_i8(aH0, b1, accH[0][1],0,0,0);\
    accH[0][2] = __builtin_amdgcn_mfma_i32_32x32x32_i8(aH0, b2, accH[0][2],0,0,0);\
    accH[0][3] = __builtin_amdgcn_mfma_i32_32x32x32_i8(aH0, b3, accH[0][3],0,0,0);\
    accH[1][0] = __builtin_amdgcn_mfma_i32_32x32x32_i8(aH1, b0, accH[1][0],0,0,0);\
    accH[1][1] = __builtin_amdgcn_mfma_i32_32x32x32_i8(aH1, b1, accH[1][1],0,0,0);\
    accH[1][2] = __builtin_amdgcn_mfma_i32_32x32x32_i8(aH1, b2, accH[1][2],0,0,0);\
    accH[1][3] = __builtin_amdgcn_mfma_i32_32x32x32_i8(aH1, b3, accH[1][3],0,0,0);

// S = x_q/D @ (w_q/D)^T exact in int32 via 2-plane i8 MFMA (32x32x32).
// 4 waves x 64x128 output each: halves LDS read traffic per MFMA
// (64 ds_read_b128/tile/CU vs 96 for 8x 64x64). Register pipeline with
// counted lgkmcnt(8); one barrier + counted vmcnt per K-tile; depth-3
// DMA prefetch. 1 wave/SIMD (~360 VGPR).
__global__ __launch_bounds__(256, 1) void pi_gemm_kernel(
    const int8_t* __restrict__ xlo, const int8_t* __restrict__ xhi,
    const int8_t* __restrict__ w8, const float* __restrict__ bias,
    float* __restrict__ out)
{
    __shared__ int8_t lds[NBUF][BUF_BYTES];   // 128 KiB

    const int tid = threadIdx.x;
    const int wid = tid >> 6;       // 0..3
    const int lane = tid & 63;

    // XCD-aware swizzle (nwg = 1024, divisible by 8 -> bijective)
    const int nwg = gridDim.x;
    const int cpx = nwg >> 3;
    const int swz = (blockIdx.x & 7) * cpx + (blockIdx.x >> 3);
    const int tn = swz & 15;        // NN/BN = 16
    const int tm = swz >> 4;        // MM/BM = 64
    const int m0 = tm * BM;
    const int n0 = tn * BN;

    // 4 waves as 2(M) x 2(N): each owns a 64x128 output sub-tile
    const int wm = (wid >> 1) * 64;
    const int wn = (wid & 1) * 128;

    // ---- lane constants ----
    const int laneRow = lane & 31;
    const int laneHi  = lane >> 5;
    const int laneXor = (lane >> 1) & 3;
    const int srow  = lane >> 2;
    const int gslot = ((lane & 3) ^ ((lane >> 3) & 3)) << 4;

    // stage half a K-tile: part0 = A lo+hi (4 loads), part1 = B (4 loads)
    auto stage = [&](int buf, int t, int part) {
        const size_t k0 = (size_t)t * BK;
        int8_t* base = &lds[buf][0];
        if (part == 0) {
            #pragma unroll
            for (int c = 0; c < 2; ++c) {
                const int chunk = 2 * wid + c;          // 0..7
                const int r = chunk * 16 + srow;        // 0..127
                const int8_t* sa = xlo + (size_t)(m0 + r) * KK + k0 + gslot;
                __builtin_amdgcn_global_load_lds((as1_cptr)(const void*)sa,
                    (as3_ptr)(void*)(base + chunk * 1024), 16, 0, 0);
                const int8_t* sh = xhi + (size_t)(m0 + r) * KK + k0 + gslot;
                __builtin_amdgcn_global_load_lds((as1_cptr)(const void*)sh,
                    (as3_ptr)(void*)(base + OFF_AHI + chunk * 1024), 16, 0, 0);
            }
        } else {
            #pragma unroll
            for (int c = 0; c < 4; ++c) {
                const int chunk = 4 * wid + c;          // 0..15
                const int r = chunk * 16 + srow;        // 0..255
                const int8_t* sb = w8 + (size_t)(n0 + r) * KK + k0 + gslot;
                __builtin_amdgcn_global_load_lds((as1_cptr)(const void*)sb,
                    (as3_ptr)(void*)(base + OFF_B + chunk * 1024), 16, 0, 0);
            }
        }
    };

    // swizzled fragment read: row-major [rows][64B], 16B slot XOR'd per row
    auto ldFrag = [&](const int8_t* plane, int rbase, int kslot) -> int4v {
        const int row = rbase + laneRow;
        const int sl = ((kslot + laneHi) ^ laneXor) << 4;
        return *(const int4v*)(plane + row * BK + sl);
    };

    const int16v zero = {0,0,0,0,0,0,0,0,0,0,0,0,0,0,0,0};
    int16v accL[2][4], accH[2][4];
    #pragma unroll
    for (int i = 0; i < 2; ++i)
        #pragma unroll
        for (int j = 0; j < 4; ++j) { accL[i][j] = zero; accH[i][j] = zero; }

    // prologue: DMA tiles 0,1,2 into buffers 0,1,2 (24 loads outstanding)
    stage(0, 0, 0); stage(0, 0, 1);
    stage(1, 1, 0); stage(1, 1, 1);
    stage(2, 2, 0); stage(2, 2, 1);
    asm volatile("s_waitcnt vmcnt(8)" ::: "memory");   // tiles 0,1 landed
    __builtin_amdgcn_s_barrier();

    // preload setA = frags for (tile 0, k-half 0)
    int4v aL0A = ldFrag(&lds[0][0],       wm,      0);
    int4v aL1A = ldFrag(&lds[0][0],       wm + 32, 0);
    int4v aH0A = ldFrag(&lds[0][OFF_AHI], wm,      0);
    int4v aH1A = ldFrag(&lds[0][OFF_AHI], wm + 32, 0);
    int4v b0A  = ldFrag(&lds[0][OFF_B],   wn,      0);
    int4v b1A  = ldFrag(&lds[0][OFF_B],   wn + 32, 0);
    int4v b2A  = ldFrag(&lds[0][OFF_B],   wn + 64, 0);
    int4v b3A  = ldFrag(&lds[0][OFF_B],   wn + 96, 0);
    int4v aL0B, aL1B, aH0B, aH1B, b0B, b1B, b2B, b3B;

    int cbuf = 0;
    for (int t = 0; t < NKT; ++t) {
        if (t > 0) {
            if (t < NKT - 2) { asm volatile("s_waitcnt vmcnt(8)" ::: "memory"); }
            else             { asm volatile("s_waitcnt vmcnt(0)" ::: "memory"); }
            __builtin_amdgcn_s_barrier();
        }

        const int8_t* bAlo = &lds[cbuf][0];
        const int8_t* bAhi = &lds[cbuf][OFF_AHI];
        const int8_t* bB   = &lds[cbuf][OFF_B];
        const int nbuf = (cbuf + 1) & 3;

        // ---- phase 0: load setB (this tile, k-half 1); MFMA setA ----
        aL0B = ldFrag(bAlo, wm,      2);
        aL1B = ldFrag(bAlo, wm + 32, 2);
        aH0B = ldFrag(bAhi, wm,      2);
        aH1B = ldFrag(bAhi, wm + 32, 2);
        b0B  = ldFrag(bB,   wn,      2);
        b1B  = ldFrag(bB,   wn + 32, 2);
        b2B  = ldFrag(bB,   wn + 64, 2);
        b3B  = ldFrag(bB,   wn + 96, 2);
        if (t + 3 < NKT) stage((cbuf + 3) & 3, t + 3, 0);
        __builtin_amdgcn_sched_barrier(0);
        asm volatile("s_waitcnt lgkmcnt(8)" ::: "memory");  // setA done; setB in flight
        __builtin_amdgcn_sched_barrier(0);
        __builtin_amdgcn_s_setprio(1);
        MFMA16(aL0A, aL1A, aH0A, aH1A, b0A, b1A, b2A, b3A)
        __builtin_amdgcn_s_setprio(0);

        // ---- phase 1: load setA' (next tile, k-half 0); MFMA setB ----
        if (t + 1 < NKT) {
            aL0A = ldFrag(&lds[nbuf][0],       wm,      0);
            aL1A = ldFrag(&lds[nbuf][0],       wm + 32, 0);
            aH0A = ldFrag(&lds[nbuf][OFF_AHI], wm,      0);
            aH1A = ldFrag(&lds[nbuf][OFF_AHI], wm + 32, 0);
            b0A  = ldFrag(&lds[nbuf][OFF_B],   wn,      0);
            b1A  = ldFrag(&lds[nbuf][OFF_B],   wn + 32, 0);
            b2A  = ldFrag(&lds[nbuf][OFF_B],   wn + 64, 0);
            b3A  = ldFrag(&lds[nbuf][OFF_B],   wn + 96, 0);
            if (t + 3 < NKT) stage((cbuf + 3) & 3, t + 3, 1);
            __builtin_amdgcn_sched_barrier(0);
            asm volatile("s_waitcnt lgkmcnt(8)" ::: "memory");  // setB done
        } else {
            asm volatile("s_waitcnt lgkmcnt(0)" ::: "memory");
        }
        __builtin_amdgcn_sched_barrier(0);
        __builtin_amdgcn_s_setprio(1);
        MFMA16(aL0B, aL1B, aH0B, aH1B, b0B, b1B, b2B, b3B)
        __builtin_amdgcn_s_setprio(0);

        cbuf = nbuf;
    }

    // ---- epilogue ----
    // C/D 32x32 layout: col = lane&31, row = (r&3) + 8*(r>>2) + 4*(lane>>5)
    const int ccol = laneRow;
    float bs[4];
    #pragma unroll
    for (int nf = 0; nf < 4; ++nf)
        bs[nf] = bias[n0 + wn + nf * 32 + ccol] * INV_PI_UNITF;

    #pragma unroll
    for (int mf = 0; mf < 2; ++mf)
        #pragma unroll
        for (int nf = 0; nf < 4; ++nf) {
            #pragma unroll
            for (int r = 0; r < 16; ++r) {
                int S = accH[mf][nf][r] * 256 + accL[mf][nf][r];
                float T = rintf((float)S * PI_UNITF);        // q(x_q @ w_q^T)
                float o = rintf(T + bs[nf]) * PI_UNITF;      // q(c + b)
                int row = m0 + wm + mf * 32 + (r & 3) + 8 * (r >> 2) + 4 * laneHi;
                int col = n0 + wn + nf * 32 + ccol;
                out[(size_t)row * NN + col] = o;
            }
        }
}

extern "C" void kernel_launch(void* const* d_in, const int* in_sizes, int n_in,
                              void* d_out, int out_size, void* d_ws, size_t ws_size,
                              hipStream_t stream) {
    const float* x = (const float*)d_in[0];     // [8192, 4096]
    const float* w = (const float*)d_in[1];     // [4096, 4096]
    const float* b = (const float*)d_in[2];     // [4096]
    float* out = (float*)d_out;                 // [8192, 4096]

    int8_t* xlo = (int8_t*)d_ws;
    int8_t* xhi = xlo + (size_t)MM * KK;
    int8_t* w8  = xhi + (size_t)MM * KK;        // 80 MB of workspace

    quant_x_kernel<<<2048, 256, 0, stream>>>(x, (uint32_t*)xlo, (uint32_t*)xhi, MM * KK / 4);
    quant_w_kernel<<<2048, 256, 0, stream>>>(w, (uint32_t*)w8, NN * KK / 4);

    pi_gemm_kernel<<<(MM / BM) * (NN / BN), 256, 0, stream>>>(xlo, xhi, w8, b, out);
}